// Round 9
// baseline (42726.788 us; speedup 1.0000x reference)
//
#include <hip/hip_runtime.h>

#define TSTEPS 8192
#define HDIM   1024
#define NLAYER 4
#define NB     256          // 4 groups x 64 blocks, persistent, 1 block/CU
#define NT     512          // 8 waves/block
#define GB     64           // blocks per group (per layer)
#define EPB    16           // h elements per block (2 per wave)
#define RING   32           // ring depth (layer boundary), pairs
#define XPRE   4            // x prefetch depth (LDS slots)

typedef float    f32x4 __attribute__((ext_vector_type(4)));
typedef unsigned u32x4 __attribute__((ext_vector_type(4)));
typedef unsigned long long u64;

struct GruParams {
  const float* xs;
  const float* Wih[NLAYER];
  const float* Whh[NLAYER];
  const float* bias[NLAYER];
  const float* bn[NLAYER];
  float* out;      // d_out (written by group 3)
  int*   ctags;    // ws: NB per-block ring-consume tags
  u64*   hbp;      // ws: NLAYER * 2 * HDIM (value,epoch) pairs
  u64*   ringp;    // ws: 3 * RING * HDIM (value,epoch) pairs
};

__device__ __forceinline__ float sigmoidf_(float x) {
  return 1.0f / (1.0f + __expf(-x));
}
__device__ __forceinline__ float tanhf_(float x) {
  const float e = __expf(2.0f * x);
  return 1.0f - 2.0f / (e + 1.0f);
}
__device__ __forceinline__ float rfl_(float x) {
  return __int_as_float(__builtin_amdgcn_readfirstlane(__float_as_int(x)));
}

// Poll-gather one 1024-element row of (value,epoch) pairs (this lane's 16)
// until every epoch == e, then stage values into lds[0..1023].
// The gather IS the readiness check: one IF hop, no tags, no store-ack.
__device__ __forceinline__ void poll_stage_row_(const u64* buf, unsigned e,
                                                float* lds, int lane) {
  const u64* p0 = buf + lane * 4;
  u32x4 r0, r1, r2, r3, r4, r5, r6, r7;
  for (;;) {
    asm volatile(
        "global_load_dwordx4 %0, %8, off sc1\n\t"
        "global_load_dwordx4 %1, %9, off sc1\n\t"
        "global_load_dwordx4 %2, %10, off sc1\n\t"
        "global_load_dwordx4 %3, %11, off sc1\n\t"
        "global_load_dwordx4 %4, %12, off sc1\n\t"
        "global_load_dwordx4 %5, %13, off sc1\n\t"
        "global_load_dwordx4 %6, %14, off sc1\n\t"
        "global_load_dwordx4 %7, %15, off sc1\n\t"
        "s_waitcnt vmcnt(0)"
        : "=&v"(r0), "=&v"(r1), "=&v"(r2), "=&v"(r3),
          "=&v"(r4), "=&v"(r5), "=&v"(r6), "=&v"(r7)
        : "v"(p0), "v"(p0 + 2), "v"(p0 + 256), "v"(p0 + 258),
          "v"(p0 + 512), "v"(p0 + 514), "v"(p0 + 768), "v"(p0 + 770)
        : "memory");
    bool ok = (r0.y == e) & (r0.w == e) & (r1.y == e) & (r1.w == e) &
              (r2.y == e) & (r2.w == e) & (r3.y == e) & (r3.w == e) &
              (r4.y == e) & (r4.w == e) & (r5.y == e) & (r5.w == e) &
              (r6.y == e) & (r6.w == e) & (r7.y == e) & (r7.w == e);
    if (__all(ok)) break;
    __builtin_amdgcn_s_sleep(1);
  }
  f32x4 v;
  v.x = __uint_as_float(r0.x); v.y = __uint_as_float(r0.z);
  v.z = __uint_as_float(r1.x); v.w = __uint_as_float(r1.z);
  *reinterpret_cast<f32x4*>(&lds[0 * 256 + lane * 4]) = v;
  v.x = __uint_as_float(r2.x); v.y = __uint_as_float(r2.z);
  v.z = __uint_as_float(r3.x); v.w = __uint_as_float(r3.z);
  *reinterpret_cast<f32x4*>(&lds[1 * 256 + lane * 4]) = v;
  v.x = __uint_as_float(r4.x); v.y = __uint_as_float(r4.z);
  v.z = __uint_as_float(r5.x); v.w = __uint_as_float(r5.z);
  *reinterpret_cast<f32x4*>(&lds[2 * 256 + lane * 4]) = v;
  v.x = __uint_as_float(r6.x); v.y = __uint_as_float(r6.z);
  v.z = __uint_as_float(r7.x); v.w = __uint_as_float(r7.z);
  *reinterpret_cast<f32x4*>(&lds[3 * 256 + lane * 4]) = v;
}

__device__ __forceinline__ void stage_plain_row_(const float* row, float* lds,
                                                 int lane) {
#pragma unroll
  for (int i = 0; i < 4; ++i)
    *reinterpret_cast<f32x4*>(&lds[i * 256 + lane * 4]) =
        *reinterpret_cast<const f32x4*>(row + i * 256 + lane * 4);
}

__device__ __forceinline__ int lds_ld_acq_(const int* p) {
  return __hip_atomic_load(p, __ATOMIC_ACQUIRE, __HIP_MEMORY_SCOPE_WORKGROUP);
}
__device__ __forceinline__ void lds_st_rel_(int* p, int v) {
  __hip_atomic_store(p, v, __ATOMIC_RELEASE, __HIP_MEMORY_SCOPE_WORKGROUP);
}
__device__ __forceinline__ void lds_add_(int* p) {
  __hip_atomic_fetch_add(p, 1, __ATOMIC_RELEASE, __HIP_MEMORY_SCOPE_WORKGROUP);
}

// Layer-pipelined persistent GRU, epoch-carrying dataflow, NO block barrier
// in the main loop: waves decouple via LDS flags + consumption counters, so
// upstream/downstream jitter is absorbed by slack instead of propagated.
__global__ __attribute__((amdgpu_flat_work_group_size(NT, NT),
                          amdgpu_waves_per_eu(2, 2)))
void gru_pipe(GruParams p) {
  __shared__ float xst[XPRE][HDIM];
  __shared__ float hst[2][HDIM];
  __shared__ int xflag[XPRE];   // tick currently staged in slot
  __shared__ int hflag[2];      // tick currently staged in parity buf
  __shared__ int xcnt[XPRE];    // cumulative consumers of slot
  __shared__ int hcnt[2];       // cumulative consumers of parity buf
  const int tid  = threadIdx.x;
  const int lane = tid & 63;
  const int wave = tid >> 6;
  const int blk  = blockIdx.x;
  const int g    = blk >> 6;
  const int m    = blk & 63;
  const int j0   = m * EPB + wave * 2;

  // ---- weights: 12 rows (2 elems x (3 ih + 3 hh)) -> 48 f32x4 on-chip ----
  const float* Wih = p.Wih[g];
  const float* Whh = p.Whh[g];
  f32x4 w4[48];
#pragma unroll
  for (int e = 0; e < 2; ++e) {
#pragma unroll
    for (int dd = 0; dd < 6; ++dd) {
      const float* W = (dd < 3) ? Wih : Whh;
      const int gate = (dd < 3) ? dd : dd - 3;
      const float* src = W + ((size_t)gate * HDIM + (j0 + e)) * HDIM + lane * 4;
#pragma unroll
      for (int i = 0; i < 4; ++i)
        w4[(e * 6 + dd) * 4 + i] = *reinterpret_cast<const f32x4*>(src + i * 256);
    }
  }
  const float bA0 = rfl_(p.bias[g][j0]);
  const float bA1 = rfl_(p.bias[g][HDIM + j0]);
  const float bA2 = rfl_(p.bias[g][2 * HDIM + j0]);
  const float bnA = rfl_(p.bn[g][j0]);
  const float bB0 = rfl_(p.bias[g][j0 + 1]);
  const float bB1 = rfl_(p.bias[g][HDIM + j0 + 1]);
  const float bB2 = rfl_(p.bias[g][2 * HDIM + j0 + 1]);
  const float bnB = rfl_(p.bn[g][j0 + 1]);
  float hregA = 0.f, hregB = 0.f;

  u64* hp = p.hbp + (size_t)g * 2 * HDIM;
  const u64* ring_in  = p.ringp + (size_t)(g - 1) * RING * HDIM;  // g>0
  u64*       ring_out = p.ringp + (size_t)g * RING * HDIM;        // g<3

  // ---- prologue: flags/counters, zero h(0), stage x(0..3) ----
  if (tid == 0) {
    hflag[0] = 0; hflag[1] = -1;
    hcnt[0] = 0; hcnt[1] = 0;
#pragma unroll
    for (int s = 0; s < XPRE; ++s) { xflag[s] = -1; xcnt[s] = 0; }
  }
  if (wave == 0) {
    const f32x4 z4 = {0.f, 0.f, 0.f, 0.f};
#pragma unroll
    for (int i = 0; i < 4; ++i)
      *reinterpret_cast<f32x4*>(&hst[0][i * 256 + lane * 4]) = z4;
  }
  __syncthreads();   // flags initialized before wave1 publishes xflag
  if (wave == 1) {
    for (int s = 0; s < XPRE; ++s) {
      if (g == 0)
        stage_plain_row_(p.xs + (size_t)s * HDIM, &xst[s][0], lane);
      else
        poll_stage_row_(ring_in + (size_t)s * HDIM, (unsigned)(s + 1),
                        &xst[s][0], lane);
      asm volatile("s_waitcnt lgkmcnt(0)" ::: "memory");
      if (lane == 0) lds_st_rel_(&xflag[s], s);
    }
    if (g > 0 && lane == 0)
      __hip_atomic_store(&p.ctags[blk], XPRE, __ATOMIC_RELAXED,
                         __HIP_MEMORY_SCOPE_AGENT);
  }
  // no further block-wide barrier: waves proceed on flags alone

  for (int t = 0; t < TSTEPS; ++t) {
    const int s   = t & (XPRE - 1);
    const int par = t & 1;

    // ---- wait x staged; ih FMAs; signal consumption ----
    while (lds_ld_acq_(&xflag[s]) < t) { }
    __builtin_amdgcn_sched_barrier(0);
    float A_ir = 0.f, A_iz = 0.f, A_in = 0.f;
    float B_ir = 0.f, B_iz = 0.f, B_in = 0.f;
#pragma unroll
    for (int i = 0; i < 4; ++i) {
      const f32x4 v = *reinterpret_cast<const f32x4*>(&xst[s][i * 256 + lane * 4]);
#pragma unroll
      for (int q = 0; q < 4; ++q) {
        const float xq = v[q];
        A_ir = fmaf(w4[ 0 + i][q], xq, A_ir);
        A_iz = fmaf(w4[ 4 + i][q], xq, A_iz);
        A_in = fmaf(w4[ 8 + i][q], xq, A_in);
        B_ir = fmaf(w4[24 + i][q], xq, B_ir);
        B_iz = fmaf(w4[28 + i][q], xq, B_iz);
        B_in = fmaf(w4[32 + i][q], xq, B_in);
      }
    }
    if (lane == 0) lds_add_(&xcnt[s]);

    // ---- wave 0: re-stage h(t) once prior consumers are done ----
    if (wave == 0 && t > 0) {
      const int need = 8 * (t >> 1);
      while (lds_ld_acq_(&hcnt[par]) < need) { }
      poll_stage_row_(hp + (size_t)par * HDIM, (unsigned)t, &hst[par][0], lane);
      asm volatile("s_waitcnt lgkmcnt(0)" ::: "memory");
      if (lane == 0) lds_st_rel_(&hflag[par], t);
    }
    // ---- wave 2: ring-overwrite throttle (every 16 ticks, slack 16) ----
    if (wave == 2 && g < 3 && t >= 16 && (t & 15) == 0) {
      const int bound = t - 16;
      const int* tp = p.ctags + (g + 1) * GB + lane;
      for (;;) {
        const int v = __hip_atomic_load(tp, __ATOMIC_RELAXED,
                                        __HIP_MEMORY_SCOPE_AGENT);
        if (__all(v >= bound)) break;
        __builtin_amdgcn_s_sleep(4);
      }
    }

    // ---- wait h staged; hh FMAs; signal consumption ----
    while (lds_ld_acq_(&hflag[par]) < t) { }
    __builtin_amdgcn_sched_barrier(0);
    float A_hr = 0.f, A_hz = 0.f, A_hn = 0.f;
    float B_hr = 0.f, B_hz = 0.f, B_hn = 0.f;
#pragma unroll
    for (int i = 0; i < 4; ++i) {
      const f32x4 v = *reinterpret_cast<const f32x4*>(&hst[par][i * 256 + lane * 4]);
#pragma unroll
      for (int q = 0; q < 4; ++q) {
        const float hq = v[q];
        A_hr = fmaf(w4[12 + i][q], hq, A_hr);
        A_hz = fmaf(w4[16 + i][q], hq, A_hz);
        A_hn = fmaf(w4[20 + i][q], hq, A_hn);
        B_hr = fmaf(w4[36 + i][q], hq, B_hr);
        B_hz = fmaf(w4[40 + i][q], hq, B_hz);
        B_hn = fmaf(w4[44 + i][q], hq, B_hn);
      }
    }
    if (lane == 0) lds_add_(&hcnt[par]);

    // ---- reduce (r,z pre-added) + gates ----
    float sAr = A_ir + A_hr, sAz = A_iz + A_hz;
    float sBr = B_ir + B_hr, sBz = B_iz + B_hz;
#pragma unroll
    for (int off = 32; off > 0; off >>= 1) {
      sAr  += __shfl_xor(sAr,  off, 64);
      sAz  += __shfl_xor(sAz,  off, 64);
      A_in += __shfl_xor(A_in, off, 64);
      A_hn += __shfl_xor(A_hn, off, 64);
      sBr  += __shfl_xor(sBr,  off, 64);
      sBz  += __shfl_xor(sBz,  off, 64);
      B_in += __shfl_xor(B_in, off, 64);
      B_hn += __shfl_xor(B_hn, off, 64);
    }
    const float rA = sigmoidf_(sAr + bA0);
    const float zA = sigmoidf_(sAz + bA1);
    const float nA = tanhf_(A_in + bA2 + rA * (A_hn + bnA));
    const float hA = nA + zA * (hregA - nA);
    const float rB = sigmoidf_(sBr + bB0);
    const float zB = sigmoidf_(sBz + bB1);
    const float nB = tanhf_(B_in + bB2 + rB * (B_hn + bnB));
    const float hB = nB + zB * (hregB - nB);
    hregA = hA; hregB = hB;

    // ---- publish: epoch-carrying pair stores, fire-and-forget ----
    if (lane == 0) {
      u32x4 pk;
      pk.x = __float_as_uint(hA); pk.y = (unsigned)(t + 1);
      pk.z = __float_as_uint(hB); pk.w = (unsigned)(t + 1);
      u64* hdst = hp + (size_t)((t + 1) & 1) * HDIM + j0;
      asm volatile("global_store_dwordx4 %0, %1, off sc1"
                   :: "v"(hdst), "v"(pk) : "memory");
      if (g < 3) {
        u64* rdst = ring_out + (size_t)(t & (RING - 1)) * HDIM + j0;
        asm volatile("global_store_dwordx4 %0, %1, off sc1"
                     :: "v"(rdst), "v"(pk) : "memory");
      } else {
        const u64 po = ((u64)__float_as_uint(hB) << 32) |
                       (u64)__float_as_uint(hA);
        float* od = p.out + (size_t)t * HDIM + j0;
        asm volatile("global_store_dwordx2 %0, %1, off sc1"
                     :: "v"(od), "v"(po) : "memory");
      }
    }

    // ---- wave 1 tail: stage x(t+XPRE) into slot s (4-tick jitter buffer) ----
    if (wave == 1) {
      const int tw = t + XPRE;
      if (tw < TSTEPS) {
        const int need = 8 * ((t >> 2) + 1);   // all ih-consumers of tick t done
        while (lds_ld_acq_(&xcnt[s]) < need) { }
        if (g == 0)
          stage_plain_row_(p.xs + (size_t)tw * HDIM, &xst[s][0], lane);
        else
          poll_stage_row_(ring_in + (size_t)(tw & (RING - 1)) * HDIM,
                          (unsigned)(tw + 1), &xst[s][0], lane);
        asm volatile("s_waitcnt lgkmcnt(0)" ::: "memory");
        if (lane == 0) {
          lds_st_rel_(&xflag[s], tw);
          if (g > 0)
            __hip_atomic_store(&p.ctags[blk], tw + 1, __ATOMIC_RELAXED,
                               __HIP_MEMORY_SCOPE_AGENT);
        }
      }
    }
  }
}

extern "C" void kernel_launch(void* const* d_in, const int* in_sizes, int n_in,
                              void* d_out, int out_size, void* d_ws, size_t ws_size,
                              hipStream_t stream) {
  GruParams p;
  p.xs = (const float*)d_in[0];
  for (int l = 0; l < NLAYER; ++l) {
    p.Wih[l]  = (const float*)d_in[1 + 4 * l];
    p.Whh[l]  = (const float*)d_in[2 + 4 * l];
    p.bias[l] = (const float*)d_in[3 + 4 * l];
    p.bn[l]   = (const float*)d_in[4 + 4 * l];
  }
  char* ws = (char*)d_ws;
  size_t off = 0;
  p.ctags = (int*)(ws + off);
  off += (size_t)NB * sizeof(int);
  off = (off + 255) & ~(size_t)255;
  p.hbp = (u64*)(ws + off);
  const size_t hbp_bytes = (size_t)NLAYER * 2 * HDIM * sizeof(u64);
  off += hbp_bytes;
  p.ringp = (u64*)(ws + off);
  const size_t ring_bytes = (size_t)3 * RING * HDIM * sizeof(u64);
  off += ring_bytes;
  p.out = (float*)d_out;

  // Replay safety: epochs restart at 1 each launch; clear all epoch state.
  (void)hipMemsetAsync(p.ctags, 0, (size_t)NB * sizeof(int), stream);
  (void)hipMemsetAsync(p.hbp, 0, hbp_bytes, stream);
  (void)hipMemsetAsync(p.ringp, 0, ring_bytes, stream);
  gru_pipe<<<dim3(NB), dim3(NT), 0, stream>>>(p);
}